// Round 1
// baseline (347.339 us; speedup 1.0000x reference)
//
#include <hip/hip_runtime.h>

#define NM    4096
#define NPTS  131072
#define NRAYS 1024
#define CAP   128

// LDS layout (float offsets). float4-read regions first (16B aligned).
#define OFF_W0 0      // [32][64]  padded from [32][63]
#define OFF_W1 2048   // [32][32]
#define OFF_FW 3072   // [32][32]
#define OFF_VW 4096   // [32][64]  padded from [32][59]
#define OFF_SW 6144   // [32]
#define OFF_RW 6176   // [3][32]
#define OFF_B0 6272
#define OFF_B1 6304
#define OFF_FB 6336
#define OFF_VB 6368
#define OFF_RB 6400   // 3
#define OFF_SB 6403   // 1
#define SMEM_TOT 6404

__global__ __launch_bounds__(256) void k_bucket(const float* __restrict__ pts,
                                                int* __restrict__ count,
                                                int* __restrict__ plist) {
    int n = blockIdx.x * 256 + threadIdx.x;
    if (n >= NPTS) return;
    float x = pts[3 * n + 0], y = pts[3 * n + 1], z = pts[3 * n + 2];
    int ix = (int)fminf(fmaxf(x * 16.f, 0.f), 15.f);
    int iy = (int)fminf(fmaxf(y * 16.f, 0.f), 15.f);
    int iz = (int)fminf(fmaxf(z * 16.f, 0.f), 15.f);
    int v = (ix << 8) | (iy << 4) | iz;
    int pos = atomicAdd(&count[v], 1);
    if (pos < CAP) plist[v * CAP + pos] = n;
}

__global__ __launch_bounds__(64) void k_mlp(
    const float* __restrict__ pts, const float* __restrict__ vds,
    const float* __restrict__ w0g, const float* __restrict__ b0g,
    const float* __restrict__ w1g, const float* __restrict__ b1g,
    const float* __restrict__ fwg, const float* __restrict__ fbg,
    const float* __restrict__ swg, const float* __restrict__ sbg,
    const float* __restrict__ vwg, const float* __restrict__ vbg,
    const float* __restrict__ rwg, const float* __restrict__ rbg,
    const int* __restrict__ count, const int* __restrict__ plist,
    float* __restrict__ out) {
    __shared__ float s[SMEM_TOT];
    const int v = blockIdx.x;
    const int t = threadIdx.x;
    const int c = min(count[v], CAP);
    if (c == 0) return;

    // ---- stage this voxel's weights into LDS ----
    {
        const float* g = w0g + v * 2016;                 // (32,63) -> [32][64]
        for (int i = t; i < 2048; i += 64) {
            int r = i >> 6, d = i & 63;
            s[OFF_W0 + i] = (d < 63) ? g[r * 63 + d] : 0.f;
        }
        const float4* w1s = (const float4*)(w1g + v * 1024);
        float4* w1d = (float4*)(s + OFF_W1);
        for (int i = t; i < 256; i += 64) w1d[i] = w1s[i];
        const float4* fws = (const float4*)(fwg + v * 1024);
        float4* fwd = (float4*)(s + OFF_FW);
        for (int i = t; i < 256; i += 64) fwd[i] = fws[i];
        g = vwg + v * 1888;                              // (32,59) -> [32][64]
        for (int i = t; i < 2048; i += 64) {
            int r = i >> 6, d = i & 63;
            s[OFF_VW + i] = (d < 59) ? g[r * 59 + d] : 0.f;
        }
        if (t < 32) {
            s[OFF_SW + t] = swg[v * 32 + t];
            s[OFF_B0 + t] = b0g[v * 32 + t];
            s[OFF_B1 + t] = b1g[v * 32 + t];
            s[OFF_FB + t] = fbg[v * 32 + t];
            s[OFF_VB + t] = vbg[v * 32 + t];
        }
        for (int i = t; i < 96; i += 64) s[OFF_RW + i] = rwg[v * 96 + i];
        if (t < 3) s[OFF_RB + t] = rbg[v * 3 + t];
        if (t == 3) s[OFF_SB] = sbg[v];
    }
    __syncthreads();

    const int half = t & 1;          // 2 lanes per point: each does 16 of 32 rows
    const int rb16 = half << 4;

    for (int base = 0; base < c; base += 32) {
        const int slot = base + (t >> 1);
        if (slot >= c) continue;     // pair-uniform divergence (lane pairs agree)
        const int n = plist[v * CAP + slot];

        const float px = pts[3 * n], py = pts[3 * n + 1], pz = pts[3 * n + 2];
        const int ray = n >> 7;      // N_SAMPLES = 128
        const float dx = vds[3 * ray], dy = vds[3 * ray + 1], dz = vds[3 * ray + 2];

        // ---- xyz positional encoding: [x, {sin(xf),cos(xf)} x 10] -> 63 (+1 pad) ----
        float ep[64];
        ep[0] = px; ep[1] = py; ep[2] = pz;
        {
            float f = 1.f;
            #pragma unroll
            for (int k = 0; k < 10; k++) {
                ep[3 + 6 * k + 0] = __sinf(px * f);
                ep[3 + 6 * k + 1] = __sinf(py * f);
                ep[3 + 6 * k + 2] = __sinf(pz * f);
                ep[3 + 6 * k + 3] = __cosf(px * f);
                ep[3 + 6 * k + 4] = __cosf(py * f);
                ep[3 + 6 * k + 5] = __cosf(pz * f);
                f *= 2.f;
            }
        }
        ep[63] = 0.f;

        // ---- layer 0: h = relu(W0 @ ep + b0), this lane: rows rb16..rb16+15 ----
        float h[16];
        #pragma unroll
        for (int o = 0; o < 16; o++) {
            const float4* wr = (const float4*)(s + OFF_W0 + ((rb16 + o) << 6));
            float acc = s[OFF_B0 + rb16 + o];
            #pragma unroll
            for (int j = 0; j < 16; j++) {
                float4 w = wr[j];
                acc += w.x * ep[4 * j] + w.y * ep[4 * j + 1] + w.z * ep[4 * j + 2] + w.w * ep[4 * j + 3];
            }
            h[o] = fmaxf(acc, 0.f);
        }
        // exchange -> full h[32] (shuffles before selects: both pair lanes active)
        float hf[32];
        {
            float ho[16];
            #pragma unroll
            for (int j = 0; j < 16; j++) ho[j] = __shfl_xor(h[j], 1, 64);
            #pragma unroll
            for (int j = 0; j < 16; j++) {
                hf[j]      = half ? ho[j] : h[j];
                hf[16 + j] = half ? h[j]  : ho[j];
            }
        }

        // ---- layer 1: h2 = relu(W1 @ hf + b1) ----
        float h2[16];
        #pragma unroll
        for (int o = 0; o < 16; o++) {
            const float4* wr = (const float4*)(s + OFF_W1 + ((rb16 + o) << 5));
            float acc = s[OFF_B1 + rb16 + o];
            #pragma unroll
            for (int j = 0; j < 8; j++) {
                float4 w = wr[j];
                acc += w.x * hf[4 * j] + w.y * hf[4 * j + 1] + w.z * hf[4 * j + 2] + w.w * hf[4 * j + 3];
            }
            h2[o] = fmaxf(acc, 0.f);
        }
        float h2f[32];
        {
            float ho[16];
            #pragma unroll
            for (int j = 0; j < 16; j++) ho[j] = __shfl_xor(h2[j], 1, 64);
            #pragma unroll
            for (int j = 0; j < 16; j++) {
                h2f[j]      = half ? ho[j] : h2[j];
                h2f[16 + j] = half ? h2[j] : ho[j];
            }
        }

        // ---- sigma = sw . h2f + sb (computed redundantly by both halves) ----
        float sg = s[OFF_SB];
        #pragma unroll
        for (int j = 0; j < 8; j++) {
            float4 w = ((const float4*)(s + OFF_SW))[j];
            sg += w.x * h2f[4 * j] + w.y * h2f[4 * j + 1] + w.z * h2f[4 * j + 2] + w.w * h2f[4 * j + 3];
        }

        // ---- feat = FW @ h2f + fb (no relu) ----
        float ft[16];
        #pragma unroll
        for (int o = 0; o < 16; o++) {
            const float4* wr = (const float4*)(s + OFF_FW + ((rb16 + o) << 5));
            float acc = s[OFF_FB + rb16 + o];
            #pragma unroll
            for (int j = 0; j < 8; j++) {
                float4 w = wr[j];
                acc += w.x * h2f[4 * j] + w.y * h2f[4 * j + 1] + w.z * h2f[4 * j + 2] + w.w * h2f[4 * j + 3];
            }
            ft[o] = acc;
        }

        // ---- view input: [feat(32), dir-encoding(27), pad(5)] ----
        float hv[64];
        {
            float fo[16];
            #pragma unroll
            for (int j = 0; j < 16; j++) fo[j] = __shfl_xor(ft[j], 1, 64);
            #pragma unroll
            for (int j = 0; j < 16; j++) {
                hv[j]      = half ? fo[j] : ft[j];
                hv[16 + j] = half ? ft[j] : fo[j];
            }
        }
        hv[32] = dx; hv[33] = dy; hv[34] = dz;
        {
            float f = 1.f;
            #pragma unroll
            for (int k = 0; k < 4; k++) {
                hv[35 + 6 * k + 0] = __sinf(dx * f);
                hv[35 + 6 * k + 1] = __sinf(dy * f);
                hv[35 + 6 * k + 2] = __sinf(dz * f);
                hv[35 + 6 * k + 3] = __cosf(dx * f);
                hv[35 + 6 * k + 4] = __cosf(dy * f);
                hv[35 + 6 * k + 5] = __cosf(dz * f);
                f *= 2.f;
            }
        }
        #pragma unroll
        for (int j = 59; j < 64; j++) hv[j] = 0.f;

        // ---- view layer: h3 = relu(VW @ hv + vb) ----
        float h3[16];
        #pragma unroll
        for (int o = 0; o < 16; o++) {
            const float4* wr = (const float4*)(s + OFF_VW + ((rb16 + o) << 6));
            float acc = s[OFF_VB + rb16 + o];
            #pragma unroll
            for (int j = 0; j < 16; j++) {
                float4 w = wr[j];
                acc += w.x * hv[4 * j] + w.y * hv[4 * j + 1] + w.z * hv[4 * j + 2] + w.w * hv[4 * j + 3];
            }
            h3[o] = fmaxf(acc, 0.f);
        }
        float h3f[32];
        {
            float ho[16];
            #pragma unroll
            for (int j = 0; j < 16; j++) ho[j] = __shfl_xor(h3[j], 1, 64);
            #pragma unroll
            for (int j = 0; j < 16; j++) {
                h3f[j]      = half ? ho[j] : h3[j];
                h3f[16 + j] = half ? h3[j] : ho[j];
            }
        }

        // ---- rgb = RW @ h3f + rb ----
        float r0 = s[OFF_RB + 0], r1 = s[OFF_RB + 1], r2 = s[OFF_RB + 2];
        #pragma unroll
        for (int j = 0; j < 8; j++) {
            float4 wa = ((const float4*)(s + OFF_RW))[j];
            float4 wb = ((const float4*)(s + OFF_RW + 32))[j];
            float4 wc = ((const float4*)(s + OFF_RW + 64))[j];
            float a = h3f[4 * j], b = h3f[4 * j + 1], cc = h3f[4 * j + 2], d = h3f[4 * j + 3];
            r0 += wa.x * a + wa.y * b + wa.z * cc + wa.w * d;
            r1 += wb.x * a + wb.y * b + wb.z * cc + wb.w * d;
            r2 += wc.x * a + wc.y * b + wc.z * cc + wc.w * d;
        }

        if (half == 0) {
            out[3 * n + 0] = r0;
            out[3 * n + 1] = r1;
            out[3 * n + 2] = r2;
            out[3 * NPTS + n] = sg;
        }
    }
}

extern "C" void kernel_launch(void* const* d_in, const int* in_sizes, int n_in,
                              void* d_out, int out_size, void* d_ws, size_t ws_size,
                              hipStream_t stream) {
    const float* pts = (const float*)d_in[0];
    const float* vds = (const float*)d_in[1];
    const float* w0  = (const float*)d_in[2];
    const float* b0  = (const float*)d_in[3];
    const float* w1  = (const float*)d_in[4];
    const float* b1  = (const float*)d_in[5];
    const float* fw  = (const float*)d_in[6];
    const float* fb  = (const float*)d_in[7];
    const float* sw  = (const float*)d_in[8];
    const float* sb  = (const float*)d_in[9];
    const float* vw  = (const float*)d_in[10];
    const float* vb  = (const float*)d_in[11];
    const float* rw  = (const float*)d_in[12];
    const float* rb  = (const float*)d_in[13];
    float* out = (float*)d_out;

    int* count = (int*)d_ws;
    int* plist = (int*)((char*)d_ws + NM * sizeof(int));

    hipMemsetAsync(count, 0, NM * sizeof(int), stream);
    k_bucket<<<NPTS / 256, 256, 0, stream>>>(pts, count, plist);
    k_mlp<<<NM, 64, 0, stream>>>(pts, vds, w0, b0, w1, b1, fw, fb, sw, sb,
                                 vw, vb, rw, rb, count, plist, out);
}